// Round 5
// baseline (722.541 us; speedup 1.0000x reference)
//
#include <hip/hip_runtime.h>
#include <hip/hip_bf16.h>

// Problem constants
#define T_DIM 64
#define B_DIM 512
#define D_DIM 1536
#define H_DIM 1024
#define M_DIM (T_DIM * B_DIM)   // 32768 rows through the MLP
#define DISCOUNT 0.997f
#define LAM 0.95f

// GEMM tiling: 256x256 C-tile, 512 threads (8 waves, 2m x 4n), each wave
// 128x64 (8x4 MFMA tiles). BK=64, double-buffered LDS (128 KB dynamic).
// Intensity: 64 KB staged -> 8.39 MFLOP = 131 FLOP/B; LDS fragment reads
// 384 B/MFMA (12 reads per 32 MFMAs) vs 512 B/MFMA for the 64x64 wave tile.
#define BM 256
#define BN 256
#define BK 64
#define TILES_M 128
#define TILES_N 4
#define N_XCD 8
#define GEMM_LDS_BYTES (2 * (BM + BN) * BK * 2)   // 131072

typedef __bf16 bf16x8 __attribute__((ext_vector_type(8)));
typedef float  f32x4  __attribute__((ext_vector_type(4)));

__device__ __forceinline__ void async_load16(const void* g, void* l) {
    __builtin_amdgcn_global_load_lds(
        (const __attribute__((address_space(1))) void*)g,
        (__attribute__((address_space(3))) void*)l,
        16, 0, 0);
}

__device__ __forceinline__ unsigned short f2bf_raw(float f) {
    __hip_bfloat16 h = __float2bfloat16(f);
    return *reinterpret_cast<unsigned short*>(&h);
}

// ---------------------------------------------------------------------------
// feat fp32 -> bf16, vectorized (float4 in, ushort4 out)
// ---------------------------------------------------------------------------
__global__ __launch_bounds__(256) void cvt_bf16_kernel(
    const float* __restrict__ x, __hip_bfloat16* __restrict__ y, long n4) {
    long i = (long)blockIdx.x * blockDim.x + threadIdx.x;
    if (i >= n4) return;
    float4 v = reinterpret_cast<const float4*>(x)[i];
    ushort4 o;
    o.x = f2bf_raw(v.x);
    o.y = f2bf_raw(v.y);
    o.z = f2bf_raw(v.z);
    o.w = f2bf_raw(v.w);
    reinterpret_cast<ushort4*>(y)[i] = o;
}

// ---------------------------------------------------------------------------
// All 4 weight transposes in one launch. W (K x N fp32) -> Wt (N x K bf16).
// ---------------------------------------------------------------------------
__global__ __launch_bounds__(256) void transpose_cvt_all_kernel(
    const float* __restrict__ W0, const float* __restrict__ W1,
    const float* __restrict__ W2, const float* __restrict__ W3,
    __hip_bfloat16* __restrict__ T0, __hip_bfloat16* __restrict__ T1,
    __hip_bfloat16* __restrict__ T2, __hip_bfloat16* __restrict__ T3) {
    __shared__ float tile[32][33];
    int z = blockIdx.z;
    const float* W;
    __hip_bfloat16* Tt;
    int K;
    if (z == 0)      { W = W0; Tt = T0; K = D_DIM; }
    else if (z == 1) { W = W1; Tt = T1; K = H_DIM; }
    else if (z == 2) { W = W2; Tt = T2; K = H_DIM; }
    else             { W = W3; Tt = T3; K = H_DIM; }
    int k0 = blockIdx.x * 32, n0 = blockIdx.y * 32;
    if (k0 >= K) return;
    int tx = threadIdx.x, ty = threadIdx.y;  // 32 x 8
    #pragma unroll
    for (int r = ty; r < 32; r += 8)
        tile[r][tx] = W[(size_t)(k0 + r) * H_DIM + n0 + tx];
    __syncthreads();
    #pragma unroll
    for (int r = ty; r < 32; r += 8)
        Tt[(size_t)(n0 + r) * K + k0 + tx] = __float2bfloat16(tile[tx][r]);
}

// ---------------------------------------------------------------------------
// C[m][n] = silu( sum_k A[m][k]*Bt[n][k] + bias[n] ). 256x256 tile,
// 512 threads / 8 waves (2m x 4n), per-wave 128x64 = 8x4 MFMA tiles.
// Pipelined dbuf K-loop (r3-verified): vmcnt(0) lands a full compute phase
// after issue -> near-free; one raw s_barrier per iter; next tile's loads
// stay in flight across the MFMA phase. 1 block/CU (128 KB LDS, ~208 regs).
//
// Fused value head: if Wo != null, rows' silu outputs are dotted with Wo,
// shuffle-reduced across the 16 lanes sharing a row, and atomicAdd'ed into
// value[] (4 N-tile blocks contribute partials). If C == null, store skipped.
//
// XCD swizzle: xcd = l%8; 4 adjacent local blocks share one 256-row A panel;
// Wt N-slice (512 KB) L2-resident. LDS XOR swizzle (global-side permute):
// r2 measured 0 bank conflicts with this scheme.
// ---------------------------------------------------------------------------
__global__ __launch_bounds__(512, 2) void gemm_silu_kernel(
    const __hip_bfloat16* __restrict__ A,
    const __hip_bfloat16* __restrict__ Bt,
    const float* __restrict__ bias,
    __hip_bfloat16* __restrict__ C,
    const float* __restrict__ Wo,
    float* __restrict__ value,
    int K) {

    extern __shared__ __align__(16) __hip_bfloat16 smem[];
    __hip_bfloat16* AsBuf = smem;                    // [2][BM*BK]
    __hip_bfloat16* BsBuf = smem + 2 * BM * BK;      // [2][BN*BK]

    const int tid  = threadIdx.x;
    const int wave = tid >> 6;         // 0..7
    const int lane = tid & 63;
    const int sub  = lane >> 3;        // staging row within 8-row chunk
    const int quad = lane >> 4;        // 0..3
    const int r16  = lane & 15;        // 0..15
    const int wm   = wave & 1;         // wave row (2)
    const int wn   = wave >> 1;        // wave col (4)

    // XCD-aware tile assignment: 512 blocks = 128 M-tiles x 4 N-tiles
    const int l     = blockIdx.x;
    const int xcd   = l & (N_XCD - 1);
    const int local = l >> 3;                  // 0..63
    const int tn    = local & (TILES_N - 1);   // 0..3
    const int tm    = (xcd << 4) | (local >> 2);
    const int m0 = tm * BM;
    const int n0 = tn * BN;

    // swizzled global column for this lane's staging load
    const int scol = (((lane & 7) ^ sub) << 3);

    // staging pointers: A chunks {4w..4w+3} of 32, B chunks {4w..4w+3} of 32
    const __hip_bfloat16* ga[4];
    const __hip_bfloat16* gb[4];
    #pragma unroll
    for (int i = 0; i < 4; ++i) {
        int chunk = wave * 4 + i;
        ga[i] = A  + (size_t)(m0 + chunk * 8 + sub) * K + scol;
        gb[i] = Bt + (size_t)(n0 + chunk * 8 + sub) * K + scol;
    }

    f32x4 acc[8][4];
    #pragma unroll
    for (int i = 0; i < 8; ++i)
        #pragma unroll
        for (int j = 0; j < 4; ++j)
            acc[i][j] = (f32x4){0.f, 0.f, 0.f, 0.f};

    const int niter = K / BK;

    // prologue: tile 0 -> buffer 0
    #pragma unroll
    for (int i = 0; i < 4; ++i) {
        async_load16(ga[i], &AsBuf[(wave * 4 + i) * 512]); ga[i] += BK;
        async_load16(gb[i], &BsBuf[(wave * 4 + i) * 512]); gb[i] += BK;
    }

    int p = 0;
    for (int k = 0; k < niter; ++k) {
        asm volatile("s_waitcnt vmcnt(0)" ::: "memory");
        asm volatile("s_barrier" ::: "memory");

        if (k + 1 < niter) {
            int q = p ^ 1;
            #pragma unroll
            for (int i = 0; i < 4; ++i) {
                async_load16(ga[i], &AsBuf[q * (BM * BK) + (wave * 4 + i) * 512]); ga[i] += BK;
                async_load16(gb[i], &BsBuf[q * (BM * BK) + (wave * 4 + i) * 512]); gb[i] += BK;
            }
        }

        const __hip_bfloat16* As = &AsBuf[p * (BM * BK)];
        const __hip_bfloat16* Bs = &BsBuf[p * (BM * BK)];
        #pragma unroll
        for (int kk = 0; kk < BK; kk += 32) {
            bf16x8 bf[4];
            #pragma unroll
            for (int j = 0; j < 4; ++j) {
                int n_l = wn * 64 + j * 16 + r16;
                int sb  = ((kk >> 3) + quad) ^ (n_l & 7);
                bf[j] = *reinterpret_cast<const bf16x8*>(&Bs[n_l * BK + sb * 8]);
            }
            #pragma unroll
            for (int i = 0; i < 8; ++i) {
                int m_l = wm * 128 + i * 16 + r16;
                int sa  = ((kk >> 3) + quad) ^ (m_l & 7);
                bf16x8 af = *reinterpret_cast<const bf16x8*>(&As[m_l * BK + sa * 8]);
                #pragma unroll
                for (int j = 0; j < 4; ++j)
                    acc[i][j] = __builtin_amdgcn_mfma_f32_16x16x32_bf16(
                        af, bf[j], acc[i][j], 0, 0, 0);
            }
        }
        p ^= 1;
    }

    // epilogue: bias + SiLU (+ optional C store, + optional fused value dot)
    // C/D layout: col = lane&15, row = quad*4 + reg   [verified m89]
    const bool do_c = (C != nullptr);
    const bool do_v = (Wo != nullptr);
    float rowsum[8][4];
    #pragma unroll
    for (int i = 0; i < 8; ++i)
        #pragma unroll
        for (int rr = 0; rr < 4; ++rr) rowsum[i][rr] = 0.f;

    #pragma unroll
    for (int j = 0; j < 4; ++j) {
        int col = n0 + wn * 64 + j * 16 + r16;
        float bj = bias[col];
        float wj = do_v ? Wo[col] : 0.f;
        #pragma unroll
        for (int i = 0; i < 8; ++i) {
            int row_base = m0 + wm * 128 + i * 16 + quad * 4;
            #pragma unroll
            for (int rr = 0; rr < 4; ++rr) {
                float v = acc[i][j][rr] + bj;
                float s = v / (1.f + __expf(-v));
                if (do_c)
                    C[(size_t)(row_base + rr) * H_DIM + col] = __float2bfloat16(s);
                rowsum[i][rr] += s * wj;
            }
        }
    }
    if (do_v) {
        #pragma unroll
        for (int i = 0; i < 8; ++i) {
            #pragma unroll
            for (int rr = 0; rr < 4; ++rr) {
                float rs = rowsum[i][rr];
                rs += __shfl_xor(rs, 1, 64);
                rs += __shfl_xor(rs, 2, 64);
                rs += __shfl_xor(rs, 4, 64);
                rs += __shfl_xor(rs, 8, 64);
                if (r16 == 0) {
                    int row = m0 + wm * 128 + i * 16 + quad * 4 + rr;
                    atomicAdd(&value[row], rs);
                }
            }
        }
    }
}

// ---------------------------------------------------------------------------
// GAE backward scan. value holds partial dots (needs +bo). out: ret, baseline.
// ---------------------------------------------------------------------------
__global__ __launch_bounds__(64) void gae_kernel(
    const float* __restrict__ value,
    const float* __restrict__ reward,
    const float* __restrict__ cont,
    const float* __restrict__ bo_p,
    float* __restrict__ out) {
    int b = blockIdx.x * blockDim.x + threadIdx.x;
    if (b >= B_DIM) return;
    float bo = bo_p[0];
    float adv = 0.f;
    float v_next = value[(T_DIM - 1) * B_DIM + b] + bo;
    for (int t = T_DIM - 2; t >= 0; --t) {
        float v_t  = value[t * B_DIM + b] + bo;
        float disc = cont[(t + 1) * B_DIM + b] * DISCOUNT;
        float delta = reward[t * B_DIM + b] + disc * v_next - v_t;
        adv = delta + disc * LAM * adv;
        out[t * B_DIM + b] = adv + v_t;                           // ret
        out[(T_DIM - 1) * B_DIM + t * B_DIM + b] = v_t;           // baseline
        v_next = v_t;
    }
}

// ---------------------------------------------------------------------------
extern "C" void kernel_launch(void* const* d_in, const int* in_sizes, int n_in,
                              void* d_out, int out_size, void* d_ws, size_t ws_size,
                              hipStream_t stream) {
    const float* feat   = (const float*)d_in[0];
    const float* reward = (const float*)d_in[1];
    const float* cont   = (const float*)d_in[2];
    const float* W[4]   = {(const float*)d_in[3], (const float*)d_in[5],
                           (const float*)d_in[7], (const float*)d_in[9]};
    const float* bias[4] = {(const float*)d_in[4], (const float*)d_in[6],
                            (const float*)d_in[8], (const float*)d_in[10]};
    const float* Wo = (const float*)d_in[11];
    const float* bo = (const float*)d_in[12];
    float* out = (float*)d_out;

    // workspace layout
    char* ws = (char*)d_ws;
    __hip_bfloat16* Xb = (__hip_bfloat16*)ws; ws += (size_t)M_DIM * D_DIM * 2;   // 96 MB
    __hip_bfloat16* Ha = (__hip_bfloat16*)ws; ws += (size_t)M_DIM * H_DIM * 2;   // 64 MB
    __hip_bfloat16* Hb = (__hip_bfloat16*)ws; ws += (size_t)M_DIM * H_DIM * 2;   // 64 MB
    __hip_bfloat16* Wt0 = (__hip_bfloat16*)ws; ws += (size_t)H_DIM * D_DIM * 2;  // 3 MB
    __hip_bfloat16* Wt1 = (__hip_bfloat16*)ws; ws += (size_t)H_DIM * H_DIM * 2;
    __hip_bfloat16* Wt2 = (__hip_bfloat16*)ws; ws += (size_t)H_DIM * H_DIM * 2;
    __hip_bfloat16* Wt3 = (__hip_bfloat16*)ws; ws += (size_t)H_DIM * H_DIM * 2;
    float* value = (float*)ws; ws += (size_t)M_DIM * 4;

    // allow 128 KB dynamic LDS for the GEMM (host-side, capture-safe)
    (void)hipFuncSetAttribute((const void*)gemm_silu_kernel,
                              hipFuncAttributeMaxDynamicSharedMemorySize,
                              GEMM_LDS_BYTES);

    // 1. feat -> bf16
    long n4 = (long)M_DIM * D_DIM / 4;
    cvt_bf16_kernel<<<(int)((n4 + 255) / 256), 256, 0, stream>>>(feat, Xb, n4);

    // 2. all weight transposes, one launch
    transpose_cvt_all_kernel<<<dim3(D_DIM / 32, H_DIM / 32, 4), dim3(32, 8), 0, stream>>>(
        W[0], W[1], W[2], W[3], Wt0, Wt1, Wt2, Wt3);

    // 3. zero value accumulator (fused head atomicAdds partials into it)
    hipMemsetAsync(value, 0, (size_t)M_DIM * 4, stream);

    // 4. MLP GEMMs; layer 3 fuses the value-head dot and skips the C store
    const int nblocks = TILES_M * TILES_N;  // 512
    gemm_silu_kernel<<<nblocks, 512, GEMM_LDS_BYTES, stream>>>(
        Xb, Wt0, bias[0], Ha, nullptr, nullptr, D_DIM);
    gemm_silu_kernel<<<nblocks, 512, GEMM_LDS_BYTES, stream>>>(
        Ha, Wt1, bias[1], Hb, nullptr, nullptr, H_DIM);
    gemm_silu_kernel<<<nblocks, 512, GEMM_LDS_BYTES, stream>>>(
        Hb, Wt2, bias[2], Ha, nullptr, nullptr, H_DIM);
    gemm_silu_kernel<<<nblocks, 512, GEMM_LDS_BYTES, stream>>>(
        Ha, Wt3, bias[3], nullptr, Wo, value, H_DIM);

    // 5. GAE scan (adds bo to the value partials)
    gae_kernel<<<8, 64, 0, stream>>>(value, reward, cont, bo, out);
}